// Round 20
// baseline (127.988 us; speedup 1.0000x reference)
//
#include <hip/hip_runtime.h>

// ---------------------------------------------------------------------------
// SelfAttention: B=4, N=4096 tokens/batch, C=512, DQK=64
// out = gamma * softmax((X Wf)(X Wg)^T) (X Wh) + X
// Round 20: R17 + 4-tile barrier amortization — one lgkm-only barrier per
// FOUR KV-tiles (16 barriers total), 8-buffer P FIFO (read quad u&1, write
// quad (u+1)&1). V: 2 register sets, reload-after-use (2 uses/iteration).
// K: 4 sets, 2-iteration prefetch lead. 512 thr / 8 waves / 2 per SIMD /
// 1 block/CU (256-VGPR budget, no spill).
// ---------------------------------------------------------------------------

typedef __bf16 bf16x8 __attribute__((ext_vector_type(8)));
typedef __bf16 bf16x2 __attribute__((ext_vector_type(2)));
typedef float f32x4 __attribute__((ext_vector_type(4)));
typedef unsigned int u32x4 __attribute__((ext_vector_type(4)));
typedef unsigned int u32;

#define L2E 1.4426950408889634f

__device__ __forceinline__ unsigned short f2bf(float f) {
    unsigned int u = __builtin_bit_cast(unsigned int, f);
    u += 0x7fffu + ((u >> 16) & 1u);   // RNE
    return (unsigned short)(u >> 16);
}
__device__ __forceinline__ u32 cvtpk(float a, float b) {
    bf16x2 t; t[0] = (__bf16)a; t[1] = (__bf16)b;   // -> v_cvt_pk_bf16_f32
    return __builtin_bit_cast(u32, t);
}
__device__ __forceinline__ bf16x8 ld8(const void* p) {
    u32x4 u = *reinterpret_cast<const u32x4*>(p);
    return __builtin_bit_cast(bf16x8, u);
}
__device__ __forceinline__ bf16x8 ldx(const float* p) {
    float4 a = *reinterpret_cast<const float4*>(p);
    float4 b = *reinterpret_cast<const float4*>(p + 4);
    u32x4 r;
    r.x = cvtpk(a.x, a.y); r.y = cvtpk(a.z, a.w);
    r.z = cvtpk(b.x, b.y); r.w = cvtpk(b.z, b.w);
    return __builtin_bit_cast(bf16x8, r);
}
__device__ __forceinline__ f32x4 mfma16(bf16x8 a, bf16x8 b, f32x4 c) {
    return __builtin_amdgcn_mfma_f32_16x16x32_bf16(a, b, c, 0, 0, 0);
}
__device__ __forceinline__ void gl2lds16(const void* g, void* l) {
    __builtin_amdgcn_global_load_lds(
        (const __attribute__((address_space(1))) u32*)g,
        (__attribute__((address_space(3))) u32*)l, 16, 0, 0);
}

// --------------------------- prep kernel -----------------------------------
// W -> staged layout [16 chunks q][4 slots s][640 cols c][8 bf16]:
//   (q,s,c,j) = W^T[c][k=32q+8s+j]; c<64: f (x log2e), c<128: g, else h.
__global__ __launch_bounds__(256) void cvt_w_all(const float* __restrict__ kf,
                                                 const float* __restrict__ kg,
                                                 const float* __restrict__ kh,
                                                 unsigned short* __restrict__ wst) {
    int idx = blockIdx.x * 256 + threadIdx.x;   // 327680 total
    int j = idx & 7;
    int gi = idx >> 3;
    int c = gi % 640;
    int sq = gi / 640;
    int k = (sq >> 2) * 32 + (sq & 3) * 8 + j;
    float v;
    if (c < 64)       v = kf[k * 64 + c] * L2E;
    else if (c < 128) v = kg[k * 64 + (c - 64)];
    else              v = kh[k * 512 + (c - 128)];
    wst[idx] = f2bf(v);
}

// --------------------- fused projection kernel -----------------------------
// Grid dim3(256, 2). W streamed via 2x20KB LDS dbuf (global_load_lds).
// Outputs:
//   fq  [16384][64]  : f rows (Q), row-major bf16
//   kst [4][64t][4jf][2ks][64l][16B] : K A-fragment stream
//   vst [4][64t][32c16][2ks][64l][16B] : V B-fragment stream (sigma j-order)
__global__ __launch_bounds__(256, 2) void proj_k(const float* __restrict__ x,
                                                 const unsigned short* __restrict__ wst,
                                                 unsigned short* __restrict__ fq,
                                                 unsigned short* __restrict__ kst,
                                                 unsigned short* __restrict__ vst) {
    __shared__ __align__(16) unsigned char Wl[2][20480];
    __shared__ unsigned short Tl[64][72];

    int m0 = blockIdx.x * 64;
    int grp = blockIdx.y;
    int tid = threadIdx.x;
    int w = tid >> 6, l = tid & 63, g = l >> 4, i = l & 15;

    const char* wsrc = (const char*)wst + (size_t)w * 10240 + (size_t)grp * 5120 + l * 16;

#pragma unroll
    for (int s5 = 0; s5 < 5; s5++)
        gl2lds16(wsrc + s5 * 1024, &Wl[0][w * 5120 + s5 * 1024]);

    const float* xrow = x + (size_t)(m0 + 16 * w + i) * 512 + g * 8;
    bf16x8 af[16];
#pragma unroll
    for (int k = 0; k < 16; k++) af[k] = ldx(xrow + 32 * k);

    f32x4 acc[5][4];
#pragma unroll
    for (int t = 0; t < 5; t++)
#pragma unroll
        for (int cf = 0; cf < 4; cf++) acc[t][cf] = f32x4{0, 0, 0, 0};

    int rdoff = g * 5120 + i * 16;

#pragma unroll
    for (int q = 0; q < 16; q++) {
        __syncthreads();
        if (q < 15) {
            const char* src = wsrc + (size_t)(q + 1) * 40960;
#pragma unroll
            for (int s5 = 0; s5 < 5; s5++)
                gl2lds16(src + s5 * 1024, &Wl[(q + 1) & 1][w * 5120 + s5 * 1024]);
        }
        const unsigned char* Wb = &Wl[q & 1][0];
        __builtin_amdgcn_s_setprio(1);
#pragma unroll
        for (int t = 0; t < 5; t++)
#pragma unroll
            for (int cf = 0; cf < 4; cf++) {
                bf16x8 bb = ld8(Wb + rdoff + (t * 64 + 16 * cf) * 16);
                acc[t][cf] = mfma16(af[q], bb, acc[t][cf]);
            }
        __builtin_amdgcn_s_setprio(0);
    }

    int batch = m0 >> 12;
    int kt = (m0 & 4095) >> 6;   // KV tile index (this block's 64 tokens)
    unsigned short* kbase = kst + (size_t)batch * 262144 + (size_t)kt * 4096;
    unsigned short* vbase = vst + (size_t)batch * 2097152 + (size_t)kt * 32768;

#pragma unroll
    for (int t = 0; t < 5; t++) {
        if (grp == 0 && t == 0) {
#pragma unroll
            for (int cf = 0; cf < 4; cf++)
#pragma unroll
                for (int r = 0; r < 4; r++)
                    fq[(size_t)(m0 + 16 * w + 4 * g + r) * 64 + 16 * cf + i] =
                        f2bf(acc[t][cf][r]);
        } else {
            __syncthreads();
#pragma unroll
            for (int cf = 0; cf < 4; cf++) {
                ushort4 v4;
                v4.x = f2bf(acc[t][cf][0]); v4.y = f2bf(acc[t][cf][1]);
                v4.z = f2bf(acc[t][cf][2]); v4.w = f2bf(acc[t][cf][3]);
                *reinterpret_cast<ushort4*>(&Tl[16 * cf + i][16 * w + 4 * g]) = v4;
            }
            __syncthreads();
            if (grp == 0 && t == 1) {
                // g tile -> K fragment stream
#pragma unroll
                for (int ch = tid; ch < 512; ch += 256) {
                    int jf2 = ch >> 7, ks = (ch >> 6) & 1, l2 = ch & 63;
                    int g2 = l2 >> 4, i2 = l2 & 15;
                    ushort4 o0, o1;
                    o0.x = Tl[ks * 32 + 8 * g2 + 0][16 * jf2 + i2];
                    o0.y = Tl[ks * 32 + 8 * g2 + 1][16 * jf2 + i2];
                    o0.z = Tl[ks * 32 + 8 * g2 + 2][16 * jf2 + i2];
                    o0.w = Tl[ks * 32 + 8 * g2 + 3][16 * jf2 + i2];
                    o1.x = Tl[ks * 32 + 8 * g2 + 4][16 * jf2 + i2];
                    o1.y = Tl[ks * 32 + 8 * g2 + 5][16 * jf2 + i2];
                    o1.z = Tl[ks * 32 + 8 * g2 + 6][16 * jf2 + i2];
                    o1.w = Tl[ks * 32 + 8 * g2 + 7][16 * jf2 + i2];
                    unsigned short* dst = kbase + (size_t)(jf2 * 1024 + ks * 512 + l2 * 8);
                    *reinterpret_cast<ushort4*>(dst)     = o0;
                    *reinterpret_cast<ushort4*>(dst + 4) = o1;
                }
            } else {
                // V tile -> B fragment stream (sigma j-order)
                int n0 = (grp == 0) ? (t - 2) * 64 : 192 + t * 64;
#pragma unroll
                for (int ch = tid; ch < 512; ch += 256) {
                    int cc = ch >> 7, ks = (ch >> 6) & 1, l2 = ch & 63;
                    int g2 = l2 >> 4, i2 = l2 & 15;
                    int row = cc * 16 + i2;
                    int jb = 32 * ks + 4 * g2;
                    ushort4 o0, o1;
                    o0.x = Tl[row][jb + 0];  o0.y = Tl[row][jb + 1];
                    o0.z = Tl[row][jb + 2];  o0.w = Tl[row][jb + 3];
                    o1.x = Tl[row][jb + 16]; o1.y = Tl[row][jb + 17];
                    o1.z = Tl[row][jb + 18]; o1.w = Tl[row][jb + 19];
                    int c16 = (n0 >> 4) + cc;
                    unsigned short* dst = vbase + (size_t)(c16 * 1024 + ks * 512 + l2 * 8);
                    *reinterpret_cast<ushort4*>(dst)     = o0;
                    *reinterpret_cast<ushort4*>(dst + 4) = o1;
                }
            }
        }
    }
}

// --------------------------- shared-P attention ----------------------------
// Grid 256 = 4 batch x 64 q-tiles(64 rows); block 512 thr / 8 waves, 1/CU,
// 2 waves/SIMD. One lgkm-only barrier per FOUR KV-tiles; 8-buffer P FIFO
// (read quad u&1, write quad (u+1)&1). Per wave per iter: S x4 (16 MFMA) +
// K x4 reload (2-iter lead) + PV x4 (128 MFMA) with V reload-after-use
// (2 sets x 2 uses) + exp2 x16 + 4x8B P writes.
__global__ __launch_bounds__(512, 2) void attn_k(const unsigned short* __restrict__ fq,
                                                 const unsigned short* __restrict__ kst,
                                                 const unsigned short* __restrict__ vst,
                                                 const float* __restrict__ x,
                                                 const float* __restrict__ gamma,
                                                 float* __restrict__ out) {
    __shared__ __align__(16) unsigned char Pl[8][8192];   // 2 quads x 4 tiles
    __shared__ float l_lds[64];

    int bid = blockIdx.x;
    int xcd = bid & 7;
    int batch = xcd >> 1;                       // 2 XCDs per batch
    int qidx = ((xcd & 1) << 5) | (bid >> 3);   // 0..63
    int q0 = qidx * 64;

    int tid = threadIdx.x;
    int w = tid >> 6, l = tid & 63, g = l >> 4, i = l & 15;
    int jf = w >> 1, qfh = w & 1;               // S-duty

    if (tid < 64) l_lds[tid] = 0.0f;

    const unsigned short* fqb = fq + (size_t)batch * 4096 * 64;
    const char* kb = (const char*)kst + (size_t)batch * 524288;
    const char* vb = (const char*)vst + (size_t)batch * 4194304;

    // Q fragments for this wave's two S-duty qf
    bf16x8 aQ[2][2];
#pragma unroll
    for (int qf_l = 0; qf_l < 2; qf_l++)
#pragma unroll
        for (int ks = 0; ks < 2; ks++)
            aQ[qf_l][ks] = ld8(fqb + (size_t)(q0 + 16 * (2 * qfh + qf_l) + i) * 64 +
                               ks * 32 + g * 8);

    f32x4 acc[4][4];
#pragma unroll
    for (int a = 0; a < 4; a++)
#pragma unroll
        for (int b = 0; b < 4; b++) acc[a][b] = f32x4{0, 0, 0, 0};
    float lp[2] = {0.0f, 0.0f};

    int pwoff = ((2 * qfh) * 2 + (jf >> 1)) * 1024 + l * 16 + (jf & 1) * 8;
    int c16w = w * 4;   // this wave's V column-16 base (cols 64w..64w+63)

    // ---- prologue: K(0..3); V(0)->vbr_a, V(1)->vbr_b; S(0..3) -> quad 0;
    //      reload K(4..7) ----
    bf16x8 kA[4][2];
#pragma unroll
    for (int t4 = 0; t4 < 4; t4++)
#pragma unroll
        for (int ks = 0; ks < 2; ks++)
            kA[t4][ks] = ld8(kb + (size_t)(t4 * 4 + jf) * 2048 + ks * 1024 + l * 16);

    bf16x8 vbr_a[4][2], vbr_b[4][2];
#pragma unroll
    for (int cf = 0; cf < 4; cf++)
#pragma unroll
        for (int ks = 0; ks < 2; ks++) {
            vbr_a[cf][ks] = ld8(vb + (size_t)(c16w + cf) * 2048 + ks * 1024 + l * 16);
            vbr_b[cf][ks] = ld8(vb + (size_t)(32 + c16w + cf) * 2048 + ks * 1024 + l * 16);
        }

    {
        f32x4 s[4][2];
#pragma unroll
        for (int t4 = 0; t4 < 4; t4++)
#pragma unroll
            for (int qf_l = 0; qf_l < 2; qf_l++) s[t4][qf_l] = f32x4{0, 0, 0, 0};
#pragma unroll
        for (int t4 = 0; t4 < 4; t4++)
#pragma unroll
            for (int qf_l = 0; qf_l < 2; qf_l++) {
                s[t4][qf_l] = mfma16(kA[t4][0], aQ[qf_l][0], s[t4][qf_l]);
                s[t4][qf_l] = mfma16(kA[t4][1], aQ[qf_l][1], s[t4][qf_l]);
            }
#pragma unroll
        for (int t4 = 0; t4 < 4; t4++)
#pragma unroll
            for (int ks = 0; ks < 2; ks++)
                kA[t4][ks] = ld8(kb + (size_t)((4 + t4) * 4 + jf) * 2048 + ks * 1024 + l * 16);
#pragma unroll
        for (int t4 = 0; t4 < 4; t4++)
#pragma unroll
            for (int qf_l = 0; qf_l < 2; qf_l++) {
                float p0 = __builtin_amdgcn_exp2f(s[t4][qf_l][0]);
                float p1 = __builtin_amdgcn_exp2f(s[t4][qf_l][1]);
                float p2 = __builtin_amdgcn_exp2f(s[t4][qf_l][2]);
                float p3 = __builtin_amdgcn_exp2f(s[t4][qf_l][3]);
                lp[qf_l] += (p0 + p1) + (p2 + p3);
                uint2 pk2; pk2.x = cvtpk(p0, p1); pk2.y = cvtpk(p2, p3);
                *reinterpret_cast<uint2*>(&Pl[t4][0] + pwoff + qf_l * 2048) = pk2;
            }
    }

    for (int u = 0; u < 16; ++u) {
        // P quad (u&1) visible; vmcnt NOT drained (K/V prefetch in flight)
        asm volatile("s_waitcnt lgkmcnt(0)" ::: "memory");
        __builtin_amdgcn_s_barrier();

        const unsigned char* Prq = &Pl[(u & 1) * 4][0];

        // ---- S(4u+4 .. 4u+7) with kA[0..3] ----
        f32x4 s[4][2];
#pragma unroll
        for (int t4 = 0; t4 < 4; t4++)
#pragma unroll
            for (int qf_l = 0; qf_l < 2; qf_l++) s[t4][qf_l] = f32x4{0, 0, 0, 0};
#pragma unroll
        for (int t4 = 0; t4 < 4; t4++)
#pragma unroll
            for (int qf_l = 0; qf_l < 2; qf_l++) {
                s[t4][qf_l] = mfma16(kA[t4][0], aQ[qf_l][0], s[t4][qf_l]);
                s[t4][qf_l] = mfma16(kA[t4][1], aQ[qf_l][1], s[t4][qf_l]);
            }

        // ---- K(4u+8 .. 4u+11) reload (2-iteration lead) ----
#pragma unroll
        for (int t4 = 0; t4 < 4; t4++) {
            int tk = (4 * u + 8 + t4) & 63;
#pragma unroll
            for (int ks = 0; ks < 2; ks++)
                kA[t4][ks] = ld8(kb + (size_t)(tk * 4 + jf) * 2048 + ks * 1024 + l * 16);
        }

        // ---- PV(4u): quad buf 0 with vbr_a; reload vbr_a <- V(4u+2) ----
        {
            bf16x8 aP[4][2];
#pragma unroll
            for (int qf = 0; qf < 4; qf++)
#pragma unroll
                for (int ks = 0; ks < 2; ks++)
                    aP[qf][ks] = ld8(Prq + (qf * 2 + ks) * 1024 + l * 16);
            __builtin_amdgcn_s_setprio(1);
#pragma unroll
            for (int cf = 0; cf < 4; cf++)
#pragma unroll
                for (int qf = 0; qf < 4; qf++) {
                    acc[qf][cf] = mfma16(aP[qf][0], vbr_a[cf][0], acc[qf][cf]);
                    acc[qf][cf] = mfma16(aP[qf][1], vbr_a[cf][1], acc[qf][cf]);
                }
            __builtin_amdgcn_s_setprio(0);
        }
        {
            int tv = (4 * u + 2) & 63;
#pragma unroll
            for (int cf = 0; cf < 4; cf++)
#pragma unroll
                for (int ks = 0; ks < 2; ks++)
                    vbr_a[cf][ks] = ld8(vb + (size_t)(tv * 32 + c16w + cf) * 2048 +
                                        ks * 1024 + l * 16);
        }

        // ---- PV(4u+1): quad buf 1 with vbr_b; reload vbr_b <- V(4u+3) ----
        {
            bf16x8 aP[4][2];
#pragma unroll
            for (int qf = 0; qf < 4; qf++)
#pragma unroll
                for (int ks = 0; ks < 2; ks++)
                    aP[qf][ks] = ld8(Prq + 8192 + (qf * 2 + ks) * 1024 + l * 16);
            __builtin_amdgcn_s_setprio(1);
#pragma unroll
            for (int cf = 0; cf < 4; cf++)
#pragma unroll
                for (int qf = 0; qf < 4; qf++) {
                    acc[qf][cf] = mfma16(aP[qf][0], vbr_b[cf][0], acc[qf][cf]);
                    acc[qf][cf] = mfma16(aP[qf][1], vbr_b[cf][1], acc[qf][cf]);
                }
            __builtin_amdgcn_s_setprio(0);
        }
        {
            int tv = (4 * u + 3) & 63;
#pragma unroll
            for (int cf = 0; cf < 4; cf++)
#pragma unroll
                for (int ks = 0; ks < 2; ks++)
                    vbr_b[cf][ks] = ld8(vb + (size_t)(tv * 32 + c16w + cf) * 2048 +
                                        ks * 1024 + l * 16);
        }

        // ---- PV(4u+2): quad buf 2 with vbr_a; reload vbr_a <- V(4u+4) ----
        {
            bf16x8 aP[4][2];
#pragma unroll
            for (int qf = 0; qf < 4; qf++)
#pragma unroll
                for (int ks = 0; ks < 2; ks++)
                    aP[qf][ks] = ld8(Prq + 16384 + (qf * 2 + ks) * 1024 + l * 16);
            __builtin_amdgcn_s_setprio(1);
#pragma unroll
            for (int cf = 0; cf < 4; cf++)
#pragma unroll
                for (int qf = 0; qf < 4; qf++) {
                    acc[qf][cf] = mfma16(aP[qf][0], vbr_a[cf][0], acc[qf][cf]);
                    acc[qf][cf] = mfma16(aP[qf][1], vbr_a[cf][1], acc[qf][cf]);
                }
            __builtin_amdgcn_s_setprio(0);
        }
        {
            int tv = (4 * u + 4) & 63;
#pragma unroll
            for (int cf = 0; cf < 4; cf++)
#pragma unroll
                for (int ks = 0; ks < 2; ks++)
                    vbr_a[cf][ks] = ld8(vb + (size_t)(tv * 32 + c16w + cf) * 2048 +
                                        ks * 1024 + l * 16);
        }

        // ---- PV(4u+3): quad buf 3 with vbr_b; reload vbr_b <- V(4u+5) ----
        {
            bf16x8 aP[4][2];
#pragma unroll
            for (int qf = 0; qf < 4; qf++)
#pragma unroll
                for (int ks = 0; ks < 2; ks++)
                    aP[qf][ks] = ld8(Prq + 24576 + (qf * 2 + ks) * 1024 + l * 16);
            __builtin_amdgcn_s_setprio(1);
#pragma unroll
            for (int cf = 0; cf < 4; cf++)
#pragma unroll
                for (int qf = 0; qf < 4; qf++) {
                    acc[qf][cf] = mfma16(aP[qf][0], vbr_b[cf][0], acc[qf][cf]);
                    acc[qf][cf] = mfma16(aP[qf][1], vbr_b[cf][1], acc[qf][cf]);
                }
            __builtin_amdgcn_s_setprio(0);
        }
        {
            int tv = (4 * u + 5) & 63;
#pragma unroll
            for (int cf = 0; cf < 4; cf++)
#pragma unroll
                for (int ks = 0; ks < 2; ks++)
                    vbr_b[cf][ks] = ld8(vb + (size_t)(tv * 32 + c16w + cf) * 2048 +
                                        ks * 1024 + l * 16);
        }

        // ---- P(4u+4 .. 4u+7) = exp2(S), pack, write quad (u+1)&1 ----
        float msk = (u < 15) ? 1.0f : 0.0f;
        unsigned char* Pwq = &Pl[((u + 1) & 1) * 4][0];
#pragma unroll
        for (int t4 = 0; t4 < 4; t4++)
#pragma unroll
            for (int qf_l = 0; qf_l < 2; qf_l++) {
                float p0 = __builtin_amdgcn_exp2f(s[t4][qf_l][0]);
                float p1 = __builtin_amdgcn_exp2f(s[t4][qf_l][1]);
                float p2 = __builtin_amdgcn_exp2f(s[t4][qf_l][2]);
                float p3 = __builtin_amdgcn_exp2f(s[t4][qf_l][3]);
                lp[qf_l] += msk * ((p0 + p1) + (p2 + p3));
                uint2 pk2; pk2.x = cvtpk(p0, p1); pk2.y = cvtpk(p2, p3);
                *reinterpret_cast<uint2*>(Pwq + t4 * 8192 + pwoff + qf_l * 2048) = pk2;
            }
    }

    // ---- l reduction: in-wave over g, cross-wave (4 jf) via LDS atomics ----
#pragma unroll
    for (int qf_l = 0; qf_l < 2; qf_l++) {
        lp[qf_l] += __shfl_xor(lp[qf_l], 16, 64);
        lp[qf_l] += __shfl_xor(lp[qf_l], 32, 64);
    }
    if (g == 0) {
        atomicAdd(&l_lds[16 * (2 * qfh + 0) + i], lp[0]);
        atomicAdd(&l_lds[16 * (2 * qfh + 1) + i], lp[1]);
    }
    __syncthreads();

    // ---- epilogue: out = gamma*O/l + x (cols 64w..64w+63) ----
    float gam = gamma[0];
#pragma unroll
    for (int qf = 0; qf < 4; qf++) {
#pragma unroll
        for (int r = 0; r < 4; r++) {
            float linv = gam / l_lds[16 * qf + 4 * g + r];
            int n = q0 + 16 * qf + 4 * g + r;
            size_t base = ((size_t)batch * 4096 + n) * 512 + 64 * w;
#pragma unroll
            for (int cf = 0; cf < 4; cf++)
                out[base + 16 * cf + i] = acc[qf][cf][r] * linv + x[base + 16 * cf + i];
        }
    }
}

// --------------------------- launcher --------------------------------------

extern "C" void kernel_launch(void* const* d_in, const int* in_sizes, int n_in,
                              void* d_out, int out_size, void* d_ws, size_t ws_size,
                              hipStream_t stream) {
    const float* x = (const float*)d_in[0];
    const float* kf = (const float*)d_in[1];
    const float* kg = (const float*)d_in[2];
    const float* kh = (const float*)d_in[3];
    const float* gamma = (const float*)d_in[4];
    float* out = (float*)d_out;

    char* ws = (char*)d_ws;
    unsigned short* Fq  = (unsigned short*)(ws);               // 2 MB
    unsigned short* Kst = (unsigned short*)(ws + 2097152);     // 2 MB
    unsigned short* Vst = (unsigned short*)(ws + 4194304);     // 16 MB
    unsigned short* Wst = (unsigned short*)(ws + 20971520);    // 640 KB

    cvt_w_all<<<1280, 256, 0, stream>>>(kf, kg, kh, Wst);
    proj_k<<<dim3(256, 2), 256, 0, stream>>>(x, Wst, Fq, Kst, Vst);
    attn_k<<<256, 512, 0, stream>>>(Fq, Kst, Vst, x, gamma, out);
}

// Round 21
// 109.779 us; speedup vs baseline: 1.1659x; 1.1659x over previous
//
#include <hip/hip_runtime.h>

// ---------------------------------------------------------------------------
// SelfAttention: B=4, N=4096 tokens/batch, C=512, DQK=64
// out = gamma * softmax((X Wf)(X Wg)^T) (X Wh) + X
// FINAL (= Round 17 config, session best 109.8 us): shared-P attention with
// 2-tile barrier amortization at 512 thr / 8 waves / 2 per SIMD / 1 block/CU.
// One lgkm-only barrier per TWO KV-tiles; 4-buffer P FIFO; V reload-after-use
// (full iteration to land); K(+4)/(+5) prefetch. R16/R20 showed deeper
// amortization spills; R14/R18/R19 showed other scheduling levers neutral.
// ---------------------------------------------------------------------------

typedef __bf16 bf16x8 __attribute__((ext_vector_type(8)));
typedef __bf16 bf16x2 __attribute__((ext_vector_type(2)));
typedef float f32x4 __attribute__((ext_vector_type(4)));
typedef unsigned int u32x4 __attribute__((ext_vector_type(4)));
typedef unsigned int u32;

#define L2E 1.4426950408889634f

__device__ __forceinline__ unsigned short f2bf(float f) {
    unsigned int u = __builtin_bit_cast(unsigned int, f);
    u += 0x7fffu + ((u >> 16) & 1u);   // RNE
    return (unsigned short)(u >> 16);
}
__device__ __forceinline__ u32 cvtpk(float a, float b) {
    bf16x2 t; t[0] = (__bf16)a; t[1] = (__bf16)b;   // -> v_cvt_pk_bf16_f32
    return __builtin_bit_cast(u32, t);
}
__device__ __forceinline__ bf16x8 ld8(const void* p) {
    u32x4 u = *reinterpret_cast<const u32x4*>(p);
    return __builtin_bit_cast(bf16x8, u);
}
__device__ __forceinline__ bf16x8 ldx(const float* p) {
    float4 a = *reinterpret_cast<const float4*>(p);
    float4 b = *reinterpret_cast<const float4*>(p + 4);
    u32x4 r;
    r.x = cvtpk(a.x, a.y); r.y = cvtpk(a.z, a.w);
    r.z = cvtpk(b.x, b.y); r.w = cvtpk(b.z, b.w);
    return __builtin_bit_cast(bf16x8, r);
}
__device__ __forceinline__ f32x4 mfma16(bf16x8 a, bf16x8 b, f32x4 c) {
    return __builtin_amdgcn_mfma_f32_16x16x32_bf16(a, b, c, 0, 0, 0);
}
__device__ __forceinline__ void gl2lds16(const void* g, void* l) {
    __builtin_amdgcn_global_load_lds(
        (const __attribute__((address_space(1))) u32*)g,
        (__attribute__((address_space(3))) u32*)l, 16, 0, 0);
}

// --------------------------- prep kernel -----------------------------------
// W -> staged layout [16 chunks q][4 slots s][640 cols c][8 bf16]:
//   (q,s,c,j) = W^T[c][k=32q+8s+j]; c<64: f (x log2e), c<128: g, else h.
__global__ __launch_bounds__(256) void cvt_w_all(const float* __restrict__ kf,
                                                 const float* __restrict__ kg,
                                                 const float* __restrict__ kh,
                                                 unsigned short* __restrict__ wst) {
    int idx = blockIdx.x * 256 + threadIdx.x;   // 327680 total
    int j = idx & 7;
    int gi = idx >> 3;
    int c = gi % 640;
    int sq = gi / 640;
    int k = (sq >> 2) * 32 + (sq & 3) * 8 + j;
    float v;
    if (c < 64)       v = kf[k * 64 + c] * L2E;
    else if (c < 128) v = kg[k * 64 + (c - 64)];
    else              v = kh[k * 512 + (c - 128)];
    wst[idx] = f2bf(v);
}

// --------------------- fused projection kernel -----------------------------
// Grid dim3(256, 2). W streamed via 2x20KB LDS dbuf (global_load_lds).
// Outputs:
//   fq  [16384][64]  : f rows (Q), row-major bf16
//   kst [4][64t][4jf][2ks][64l][16B] : K A-fragment stream
//   vst [4][64t][32c16][2ks][64l][16B] : V B-fragment stream (sigma j-order)
__global__ __launch_bounds__(256, 2) void proj_k(const float* __restrict__ x,
                                                 const unsigned short* __restrict__ wst,
                                                 unsigned short* __restrict__ fq,
                                                 unsigned short* __restrict__ kst,
                                                 unsigned short* __restrict__ vst) {
    __shared__ __align__(16) unsigned char Wl[2][20480];
    __shared__ unsigned short Tl[64][72];

    int m0 = blockIdx.x * 64;
    int grp = blockIdx.y;
    int tid = threadIdx.x;
    int w = tid >> 6, l = tid & 63, g = l >> 4, i = l & 15;

    const char* wsrc = (const char*)wst + (size_t)w * 10240 + (size_t)grp * 5120 + l * 16;

#pragma unroll
    for (int s5 = 0; s5 < 5; s5++)
        gl2lds16(wsrc + s5 * 1024, &Wl[0][w * 5120 + s5 * 1024]);

    const float* xrow = x + (size_t)(m0 + 16 * w + i) * 512 + g * 8;
    bf16x8 af[16];
#pragma unroll
    for (int k = 0; k < 16; k++) af[k] = ldx(xrow + 32 * k);

    f32x4 acc[5][4];
#pragma unroll
    for (int t = 0; t < 5; t++)
#pragma unroll
        for (int cf = 0; cf < 4; cf++) acc[t][cf] = f32x4{0, 0, 0, 0};

    int rdoff = g * 5120 + i * 16;

#pragma unroll
    for (int q = 0; q < 16; q++) {
        __syncthreads();
        if (q < 15) {
            const char* src = wsrc + (size_t)(q + 1) * 40960;
#pragma unroll
            for (int s5 = 0; s5 < 5; s5++)
                gl2lds16(src + s5 * 1024, &Wl[(q + 1) & 1][w * 5120 + s5 * 1024]);
        }
        const unsigned char* Wb = &Wl[q & 1][0];
        __builtin_amdgcn_s_setprio(1);
#pragma unroll
        for (int t = 0; t < 5; t++)
#pragma unroll
            for (int cf = 0; cf < 4; cf++) {
                bf16x8 bb = ld8(Wb + rdoff + (t * 64 + 16 * cf) * 16);
                acc[t][cf] = mfma16(af[q], bb, acc[t][cf]);
            }
        __builtin_amdgcn_s_setprio(0);
    }

    int batch = m0 >> 12;
    int kt = (m0 & 4095) >> 6;   // KV tile index (this block's 64 tokens)
    unsigned short* kbase = kst + (size_t)batch * 262144 + (size_t)kt * 4096;
    unsigned short* vbase = vst + (size_t)batch * 2097152 + (size_t)kt * 32768;

#pragma unroll
    for (int t = 0; t < 5; t++) {
        if (grp == 0 && t == 0) {
#pragma unroll
            for (int cf = 0; cf < 4; cf++)
#pragma unroll
                for (int r = 0; r < 4; r++)
                    fq[(size_t)(m0 + 16 * w + 4 * g + r) * 64 + 16 * cf + i] =
                        f2bf(acc[t][cf][r]);
        } else {
            __syncthreads();
#pragma unroll
            for (int cf = 0; cf < 4; cf++) {
                ushort4 v4;
                v4.x = f2bf(acc[t][cf][0]); v4.y = f2bf(acc[t][cf][1]);
                v4.z = f2bf(acc[t][cf][2]); v4.w = f2bf(acc[t][cf][3]);
                *reinterpret_cast<ushort4*>(&Tl[16 * cf + i][16 * w + 4 * g]) = v4;
            }
            __syncthreads();
            if (grp == 0 && t == 1) {
                // g tile -> K fragment stream
#pragma unroll
                for (int ch = tid; ch < 512; ch += 256) {
                    int jf2 = ch >> 7, ks = (ch >> 6) & 1, l2 = ch & 63;
                    int g2 = l2 >> 4, i2 = l2 & 15;
                    ushort4 o0, o1;
                    o0.x = Tl[ks * 32 + 8 * g2 + 0][16 * jf2 + i2];
                    o0.y = Tl[ks * 32 + 8 * g2 + 1][16 * jf2 + i2];
                    o0.z = Tl[ks * 32 + 8 * g2 + 2][16 * jf2 + i2];
                    o0.w = Tl[ks * 32 + 8 * g2 + 3][16 * jf2 + i2];
                    o1.x = Tl[ks * 32 + 8 * g2 + 4][16 * jf2 + i2];
                    o1.y = Tl[ks * 32 + 8 * g2 + 5][16 * jf2 + i2];
                    o1.z = Tl[ks * 32 + 8 * g2 + 6][16 * jf2 + i2];
                    o1.w = Tl[ks * 32 + 8 * g2 + 7][16 * jf2 + i2];
                    unsigned short* dst = kbase + (size_t)(jf2 * 1024 + ks * 512 + l2 * 8);
                    *reinterpret_cast<ushort4*>(dst)     = o0;
                    *reinterpret_cast<ushort4*>(dst + 4) = o1;
                }
            } else {
                // V tile -> B fragment stream (sigma j-order)
                int n0 = (grp == 0) ? (t - 2) * 64 : 192 + t * 64;
#pragma unroll
                for (int ch = tid; ch < 512; ch += 256) {
                    int cc = ch >> 7, ks = (ch >> 6) & 1, l2 = ch & 63;
                    int g2 = l2 >> 4, i2 = l2 & 15;
                    int row = cc * 16 + i2;
                    int jb = 32 * ks + 4 * g2;
                    ushort4 o0, o1;
                    o0.x = Tl[row][jb + 0];  o0.y = Tl[row][jb + 1];
                    o0.z = Tl[row][jb + 2];  o0.w = Tl[row][jb + 3];
                    o1.x = Tl[row][jb + 16]; o1.y = Tl[row][jb + 17];
                    o1.z = Tl[row][jb + 18]; o1.w = Tl[row][jb + 19];
                    int c16 = (n0 >> 4) + cc;
                    unsigned short* dst = vbase + (size_t)(c16 * 1024 + ks * 512 + l2 * 8);
                    *reinterpret_cast<ushort4*>(dst)     = o0;
                    *reinterpret_cast<ushort4*>(dst + 4) = o1;
                }
            }
        }
    }
}

// --------------------------- shared-P attention ----------------------------
// Grid 256 = 4 batch x 64 q-tiles(64 rows); block 512 thr / 8 waves, 1/CU,
// 2 waves/SIMD (256-VGPR budget). One lgkm-only barrier per TWO KV-tiles;
// 4-buffer P FIFO (read pair u&1, write pair (u+1)&1). Per wave per iter:
// S x2 (8 MFMA) + K(+4)/(+5) prefetch + PV x2 (64 MFMA) with V reload-after-
// use (vbr_a/vbr_b, full iteration to land) + exp2 x8 + 2x8B P writes.
__global__ __launch_bounds__(512, 2) void attn_k(const unsigned short* __restrict__ fq,
                                                 const unsigned short* __restrict__ kst,
                                                 const unsigned short* __restrict__ vst,
                                                 const float* __restrict__ x,
                                                 const float* __restrict__ gamma,
                                                 float* __restrict__ out) {
    __shared__ __align__(16) unsigned char Pl[4][8192];   // [buf][qf][ks][64l][16B]
    __shared__ float l_lds[64];

    int bid = blockIdx.x;
    int xcd = bid & 7;
    int batch = xcd >> 1;                       // 2 XCDs per batch
    int qidx = ((xcd & 1) << 5) | (bid >> 3);   // 0..63
    int q0 = qidx * 64;

    int tid = threadIdx.x;
    int w = tid >> 6, l = tid & 63, g = l >> 4, i = l & 15;
    int jf = w >> 1, qfh = w & 1;               // S-duty

    if (tid < 64) l_lds[tid] = 0.0f;

    const unsigned short* fqb = fq + (size_t)batch * 4096 * 64;
    const char* kb = (const char*)kst + (size_t)batch * 524288;
    const char* vb = (const char*)vst + (size_t)batch * 4194304;

    // Q fragments for this wave's two S-duty qf
    bf16x8 aQ[2][2];
#pragma unroll
    for (int qf_l = 0; qf_l < 2; qf_l++)
#pragma unroll
        for (int ks = 0; ks < 2; ks++)
            aQ[qf_l][ks] = ld8(fqb + (size_t)(q0 + 16 * (2 * qfh + qf_l) + i) * 64 +
                               ks * 32 + g * 8);

    f32x4 acc[4][4];
#pragma unroll
    for (int a = 0; a < 4; a++)
#pragma unroll
        for (int b = 0; b < 4; b++) acc[a][b] = f32x4{0, 0, 0, 0};
    float lp[2] = {0.0f, 0.0f};

    int pwoff = ((2 * qfh) * 2 + (jf >> 1)) * 1024 + l * 16 + (jf & 1) * 8;
    int c16w = w * 4;   // this wave's V column-16 base (cols 64w..64w+63)

    // ---- prologue: K(0),K(1); V(0)->vbr_a, V(1)->vbr_b; S(0),S(1) -> P ----
    bf16x8 kAa[2], kAb[2];
    kAa[0] = ld8(kb + (size_t)jf * 2048 + l * 16);
    kAa[1] = ld8(kb + (size_t)jf * 2048 + 1024 + l * 16);
    kAb[0] = ld8(kb + (size_t)(4 + jf) * 2048 + l * 16);
    kAb[1] = ld8(kb + (size_t)(4 + jf) * 2048 + 1024 + l * 16);

    bf16x8 vbr_a[4][2], vbr_b[4][2];
#pragma unroll
    for (int cf = 0; cf < 4; cf++)
#pragma unroll
        for (int ks = 0; ks < 2; ks++) {
            vbr_a[cf][ks] = ld8(vb + (size_t)(c16w + cf) * 2048 + ks * 1024 + l * 16);
            vbr_b[cf][ks] = ld8(vb + (size_t)(32 + c16w + cf) * 2048 + ks * 1024 + l * 16);
        }

    {
        f32x4 s0[2] = {f32x4{0,0,0,0}, f32x4{0,0,0,0}};
        f32x4 s1[2] = {f32x4{0,0,0,0}, f32x4{0,0,0,0}};
#pragma unroll
        for (int qf_l = 0; qf_l < 2; qf_l++) {
            s0[qf_l] = mfma16(kAa[0], aQ[qf_l][0], s0[qf_l]);
            s0[qf_l] = mfma16(kAa[1], aQ[qf_l][1], s0[qf_l]);
            s1[qf_l] = mfma16(kAb[0], aQ[qf_l][0], s1[qf_l]);
            s1[qf_l] = mfma16(kAb[1], aQ[qf_l][1], s1[qf_l]);
        }
        kAa[0] = ld8(kb + (size_t)(8 + jf) * 2048 + l * 16);
        kAa[1] = ld8(kb + (size_t)(8 + jf) * 2048 + 1024 + l * 16);
        kAb[0] = ld8(kb + (size_t)(12 + jf) * 2048 + l * 16);
        kAb[1] = ld8(kb + (size_t)(12 + jf) * 2048 + 1024 + l * 16);
#pragma unroll
        for (int qf_l = 0; qf_l < 2; qf_l++) {
            float p0 = __builtin_amdgcn_exp2f(s0[qf_l][0]);
            float p1 = __builtin_amdgcn_exp2f(s0[qf_l][1]);
            float p2 = __builtin_amdgcn_exp2f(s0[qf_l][2]);
            float p3 = __builtin_amdgcn_exp2f(s0[qf_l][3]);
            lp[qf_l] += (p0 + p1) + (p2 + p3);
            uint2 pk2; pk2.x = cvtpk(p0, p1); pk2.y = cvtpk(p2, p3);
            *reinterpret_cast<uint2*>(&Pl[0][0] + pwoff + qf_l * 2048) = pk2;
            p0 = __builtin_amdgcn_exp2f(s1[qf_l][0]);
            p1 = __builtin_amdgcn_exp2f(s1[qf_l][1]);
            p2 = __builtin_amdgcn_exp2f(s1[qf_l][2]);
            p3 = __builtin_amdgcn_exp2f(s1[qf_l][3]);
            lp[qf_l] += (p0 + p1) + (p2 + p3);
            pk2.x = cvtpk(p0, p1); pk2.y = cvtpk(p2, p3);
            *reinterpret_cast<uint2*>(&Pl[1][0] + pwoff + qf_l * 2048) = pk2;
        }
    }

    for (int u = 0; u < 32; ++u) {
        // P pair (u&1) visible; vmcnt NOT drained (K/V prefetch in flight)
        asm volatile("s_waitcnt lgkmcnt(0)" ::: "memory");
        __builtin_amdgcn_s_barrier();

        const unsigned char* Pr0 = &Pl[(u & 1) * 2][0];
        const unsigned char* Pr1 = Pr0 + 8192;

        // ---- S(2u+2), S(2u+3) with kAa/kAb ----
        f32x4 s0[2] = {f32x4{0,0,0,0}, f32x4{0,0,0,0}};
        f32x4 s1[2] = {f32x4{0,0,0,0}, f32x4{0,0,0,0}};
#pragma unroll
        for (int qf_l = 0; qf_l < 2; qf_l++) {
            s0[qf_l] = mfma16(kAa[0], aQ[qf_l][0], s0[qf_l]);
            s0[qf_l] = mfma16(kAa[1], aQ[qf_l][1], s0[qf_l]);
            s1[qf_l] = mfma16(kAb[0], aQ[qf_l][0], s1[qf_l]);
            s1[qf_l] = mfma16(kAb[1], aQ[qf_l][1], s1[qf_l]);
        }

        // ---- K(2u+4), K(2u+5) prefetch ----
        {
            int ta = (2 * u + 4) & 63, tb = (2 * u + 5) & 63;
            const char* ka = kb + (size_t)(ta * 4 + jf) * 2048;
            const char* kp = kb + (size_t)(tb * 4 + jf) * 2048;
            kAa[0] = ld8(ka + l * 16);
            kAa[1] = ld8(ka + 1024 + l * 16);
            kAb[0] = ld8(kp + l * 16);
            kAb[1] = ld8(kp + 1024 + l * 16);
        }

        // ---- PV(2u): 32 MFMA with vbr_a ----
        {
            bf16x8 aP[4][2];
#pragma unroll
            for (int qf = 0; qf < 4; qf++)
#pragma unroll
                for (int ks = 0; ks < 2; ks++)
                    aP[qf][ks] = ld8(Pr0 + (qf * 2 + ks) * 1024 + l * 16);
            __builtin_amdgcn_s_setprio(1);
#pragma unroll
            for (int cf = 0; cf < 4; cf++)
#pragma unroll
                for (int qf = 0; qf < 4; qf++) {
                    acc[qf][cf] = mfma16(aP[qf][0], vbr_a[cf][0], acc[qf][cf]);
                    acc[qf][cf] = mfma16(aP[qf][1], vbr_a[cf][1], acc[qf][cf]);
                }
            __builtin_amdgcn_s_setprio(0);
        }
        // reload vbr_a <- V(2u+2) (full iteration to land)
        {
            int tv = (2 * u + 2) & 63;
#pragma unroll
            for (int cf = 0; cf < 4; cf++)
#pragma unroll
                for (int ks = 0; ks < 2; ks++)
                    vbr_a[cf][ks] = ld8(vb + (size_t)(tv * 32 + c16w + cf) * 2048 +
                                        ks * 1024 + l * 16);
        }

        // ---- PV(2u+1): 32 MFMA with vbr_b ----
        {
            bf16x8 aP[4][2];
#pragma unroll
            for (int qf = 0; qf < 4; qf++)
#pragma unroll
                for (int ks = 0; ks < 2; ks++)
                    aP[qf][ks] = ld8(Pr1 + (qf * 2 + ks) * 1024 + l * 16);
            __builtin_amdgcn_s_setprio(1);
#pragma unroll
            for (int cf = 0; cf < 4; cf++)
#pragma unroll
                for (int qf = 0; qf < 4; qf++) {
                    acc[qf][cf] = mfma16(aP[qf][0], vbr_b[cf][0], acc[qf][cf]);
                    acc[qf][cf] = mfma16(aP[qf][1], vbr_b[cf][1], acc[qf][cf]);
                }
            __builtin_amdgcn_s_setprio(0);
        }
        // reload vbr_b <- V(2u+3)
        {
            int tv = (2 * u + 3) & 63;
#pragma unroll
            for (int cf = 0; cf < 4; cf++)
#pragma unroll
                for (int ks = 0; ks < 2; ks++)
                    vbr_b[cf][ks] = ld8(vb + (size_t)(tv * 32 + c16w + cf) * 2048 +
                                        ks * 1024 + l * 16);
        }

        // ---- P(2u+2),P(2u+3) = exp2(S), pack, write pair (u+1)&1 ----
        float msk = (u < 31) ? 1.0f : 0.0f;
        unsigned char* Pw0 = &Pl[((u + 1) & 1) * 2][0];
        unsigned char* Pw1 = Pw0 + 8192;
#pragma unroll
        for (int qf_l = 0; qf_l < 2; qf_l++) {
            float p0 = __builtin_amdgcn_exp2f(s0[qf_l][0]);
            float p1 = __builtin_amdgcn_exp2f(s0[qf_l][1]);
            float p2 = __builtin_amdgcn_exp2f(s0[qf_l][2]);
            float p3 = __builtin_amdgcn_exp2f(s0[qf_l][3]);
            lp[qf_l] += msk * ((p0 + p1) + (p2 + p3));
            uint2 pk2; pk2.x = cvtpk(p0, p1); pk2.y = cvtpk(p2, p3);
            *reinterpret_cast<uint2*>(Pw0 + pwoff + qf_l * 2048) = pk2;
            p0 = __builtin_amdgcn_exp2f(s1[qf_l][0]);
            p1 = __builtin_amdgcn_exp2f(s1[qf_l][1]);
            p2 = __builtin_amdgcn_exp2f(s1[qf_l][2]);
            p3 = __builtin_amdgcn_exp2f(s1[qf_l][3]);
            lp[qf_l] += msk * ((p0 + p1) + (p2 + p3));
            pk2.x = cvtpk(p0, p1); pk2.y = cvtpk(p2, p3);
            *reinterpret_cast<uint2*>(Pw1 + pwoff + qf_l * 2048) = pk2;
        }
    }

    // ---- l reduction: in-wave over g, cross-wave (4 jf) via LDS atomics ----
#pragma unroll
    for (int qf_l = 0; qf_l < 2; qf_l++) {
        lp[qf_l] += __shfl_xor(lp[qf_l], 16, 64);
        lp[qf_l] += __shfl_xor(lp[qf_l], 32, 64);
    }
    if (g == 0) {
        atomicAdd(&l_lds[16 * (2 * qfh + 0) + i], lp[0]);
        atomicAdd(&l_lds[16 * (2 * qfh + 1) + i], lp[1]);
    }
    __syncthreads();

    // ---- epilogue: out = gamma*O/l + x (cols 64w..64w+63) ----
    float gam = gamma[0];
#pragma unroll
    for (int qf = 0; qf < 4; qf++) {
#pragma unroll
        for (int r = 0; r < 4; r++) {
            float linv = gam / l_lds[16 * qf + 4 * g + r];
            int n = q0 + 16 * qf + 4 * g + r;
            size_t base = ((size_t)batch * 4096 + n) * 512 + 64 * w;
#pragma unroll
            for (int cf = 0; cf < 4; cf++)
                out[base + 16 * cf + i] = acc[qf][cf][r] * linv + x[base + 16 * cf + i];
        }
    }
}

// --------------------------- launcher --------------------------------------

extern "C" void kernel_launch(void* const* d_in, const int* in_sizes, int n_in,
                              void* d_out, int out_size, void* d_ws, size_t ws_size,
                              hipStream_t stream) {
    const float* x = (const float*)d_in[0];
    const float* kf = (const float*)d_in[1];
    const float* kg = (const float*)d_in[2];
    const float* kh = (const float*)d_in[3];
    const float* gamma = (const float*)d_in[4];
    float* out = (float*)d_out;

    char* ws = (char*)d_ws;
    unsigned short* Fq  = (unsigned short*)(ws);               // 2 MB
    unsigned short* Kst = (unsigned short*)(ws + 2097152);     // 2 MB
    unsigned short* Vst = (unsigned short*)(ws + 4194304);     // 16 MB
    unsigned short* Wst = (unsigned short*)(ws + 20971520);    // 640 KB

    cvt_w_all<<<1280, 256, 0, stream>>>(kf, kg, kh, Wst);
    proj_k<<<dim3(256, 2), 256, 0, stream>>>(x, Wst, Fq, Kst, Vst);
    attn_k<<<256, 512, 0, stream>>>(Fq, Kst, Vst, x, gamma, out);
}